// Round 10
// baseline (276.139 us; speedup 1.0000x reference)
//
#include <hip/hip_runtime.h>

// ImageLRU as one GEMM: y[r,:] = W @ x[r,:], W (1024x1024, block-lower-tri)
// built on device. R10: fully fused, LDS-free GEMM:
//  - NO Xh intermediate: A-fragments are loaded as raw fp32 float4 pairs from
//    X and converted to bf16 in-register (RNE). Saves the 134 MB Xh round-trip
//    and the whole split_x pass.
//  - W-fragments direct from tiled Wh (2 MB, L2-resident), as in R9.
//  - No LDS, no barriers; 2-deep named-register pipeline (static indexing),
//    kc-loop unrolled x2; compiler emits counted vmcnt waits.
//  - mt-major block order: the 8 nb-blocks of an M-slab are co-resident, so
//    fp32 X is HBM-fetched ~once and re-served from L2/L3.
//  - 1-term precision: y = bf16(X) * bf16(W)  (absmax 8192, thr 32768).

namespace {

typedef __attribute__((ext_vector_type(8))) short short8v;
typedef __attribute__((ext_vector_type(4))) float f32x4;

__device__ inline unsigned short f2bf_rne(float f) {
    unsigned u = __builtin_bit_cast(unsigned, f);
    u += 0x7fffu + ((u >> 16) & 1u);
    return (unsigned short)(u >> 16);
}

// W tiled layout ([128 n][32 k] per 4096-ushort tile): elem (row,k) at
//   tile_base + ((k>>3)<<10) + (row<<3) + (k&7)
// -> 16 consecutive lanes of a fragment read 256 contiguous bytes.

// ---------------- prep: build Wh (bf16) in tiled layout ----------------
__global__ __launch_bounds__(256) void build_w_kernel(
    const float* __restrict__ Lre, const float* __restrict__ Lim,
    const float* __restrict__ Bre, const float* __restrict__ Bim,
    const float* __restrict__ Cre, const float* __restrict__ Cim,
    const float* __restrict__ Dm,
    unsigned short* __restrict__ Wh)
{
    const int i = blockIdx.x >> 6, j = blockIdx.x & 63;
    const int t = threadIdx.x, k = t >> 4, l = t & 15;

    const int n_g = i * 16 + k;        // W row (n dim)
    const int k_g = j * 16 + l;        // W col (k dim)
    const size_t widx = (((size_t)((n_g >> 7) * 32 + (k_g >> 5))) << 12)
                      + (((k_g >> 3) & 3) << 10) + ((n_g & 127) << 3) + (k_g & 7);

    if (j > i) { Wh[widx] = 0; return; }

    __shared__ float2 Bs[16][16];
    __shared__ float2 M[16][16];
    Bs[k][l] = make_float2(Bre[t], Bim[t]);
    M[k][l]  = make_float2(k == l ? 1.f : 0.f, 0.f);
    const int delta = i - j;
    __syncthreads();

    #pragma unroll
    for (int d = 0; d < 6; ++d) {
        const int s = 1 << d;
        if (delta & s) {
            const float lr = Lre[k], li = Lim[k];
            const float2 m0 = M[k][l];
            M[k][l] = make_float2(lr * m0.x - li * m0.y, lr * m0.y + li * m0.x);
            __syncthreads();
        } else if (j + (delta & (s - 1)) >= s) {
            float2 acc = make_float2(0.f, 0.f);
            #pragma unroll
            for (int m = 0; m < 16; ++m) {
                const float2 b = Bs[k][m], v = M[m][l];
                acc.x += b.x * v.x - b.y * v.y;
                acc.y += b.x * v.y + b.y * v.x;
            }
            __syncthreads();
            M[k][l] = acc;
            __syncthreads();
        }
    }

    float w = 0.f;
    #pragma unroll
    for (int m = 0; m < 16; ++m) {
        const float2 v = M[m][l];
        w += Cre[k * 16 + m] * v.x - Cim[k * 16 + m] * v.y;
    }
    if (i == j) w += Dm[t];
    Wh[widx] = f2bf_rne(w);
}

// ------ main GEMM: fused fp32->bf16 A, register pipeline, no LDS ------------
__global__ __launch_bounds__(256) void gemm_fused_kernel(
    const float* __restrict__ X,
    const unsigned short* __restrict__ Wh,
    float* __restrict__ Y)
{
    const int bid = blockIdx.x;
    const int nb = bid & 7;            // mt-major: same-mt nb-blocks co-resident
    const int mt = bid >> 3;
    const int t = threadIdx.x;
    const int wid = t >> 6, lane = t & 63;
    const int wr = wid >> 1, wc = wid & 1;
    const int l15 = lane & 15, lg = lane >> 4;
    const int nk = (nb + 1) * 4;       // triangular K-limit (chunks of 32), even

    f32x4 acc[4][4] = {};

    // per-lane A source base for each fragment (row-major fp32 X)
    const float* xbase[4];
    #pragma unroll
    for (int mm = 0; mm < 4; ++mm)
        xbase[mm] = X + (size_t)(mt * 128 + wr * 64 + mm * 16 + l15) * 1024 + lg * 8;

    // W fragment offsets (ushorts) within a K-chunk tile
    int wfo[4];
    #pragma unroll
    for (int nn = 0; nn < 4; ++nn)
        wfo[nn] = (lg << 10) + ((wc * 64 + nn * 16 + l15) << 3);

    float4 ar0[4][2], ar1[4][2];
    short8v b0[4], b1[4];

    auto load0 = [&](int kc) {
        #pragma unroll
        for (int mm = 0; mm < 4; ++mm) {
            const float* s = xbase[mm] + kc * 32;
            ar0[mm][0] = *reinterpret_cast<const float4*>(s);
            ar0[mm][1] = *reinterpret_cast<const float4*>(s + 4);
        }
        const size_t wb = ((size_t)(nb * 32 + kc)) << 12;
        #pragma unroll
        for (int nn = 0; nn < 4; ++nn)
            b0[nn] = *reinterpret_cast<const short8v*>(Wh + wb + wfo[nn]);
    };
    auto load1 = [&](int kc) {
        #pragma unroll
        for (int mm = 0; mm < 4; ++mm) {
            const float* s = xbase[mm] + kc * 32;
            ar1[mm][0] = *reinterpret_cast<const float4*>(s);
            ar1[mm][1] = *reinterpret_cast<const float4*>(s + 4);
        }
        const size_t wb = ((size_t)(nb * 32 + kc)) << 12;
        #pragma unroll
        for (int nn = 0; nn < 4; ++nn)
            b1[nn] = *reinterpret_cast<const short8v*>(Wh + wb + wfo[nn]);
    };

    auto cvt8 = [&](const float4& a, const float4& b) -> short8v {
        short8v r;
        r[0] = (short)f2bf_rne(a.x); r[1] = (short)f2bf_rne(a.y);
        r[2] = (short)f2bf_rne(a.z); r[3] = (short)f2bf_rne(a.w);
        r[4] = (short)f2bf_rne(b.x); r[5] = (short)f2bf_rne(b.y);
        r[6] = (short)f2bf_rne(b.z); r[7] = (short)f2bf_rne(b.w);
        return r;
    };

    auto mfma0 = [&]() {
        short8v ah[4];
        #pragma unroll
        for (int mm = 0; mm < 4; ++mm) ah[mm] = cvt8(ar0[mm][0], ar0[mm][1]);
        #pragma unroll
        for (int mm = 0; mm < 4; ++mm)
            #pragma unroll
            for (int nn = 0; nn < 4; ++nn)
                acc[mm][nn] = __builtin_amdgcn_mfma_f32_16x16x32_bf16(
                    ah[mm], b0[nn], acc[mm][nn], 0, 0, 0);
    };
    auto mfma1 = [&]() {
        short8v ah[4];
        #pragma unroll
        for (int mm = 0; mm < 4; ++mm) ah[mm] = cvt8(ar1[mm][0], ar1[mm][1]);
        #pragma unroll
        for (int mm = 0; mm < 4; ++mm)
            #pragma unroll
            for (int nn = 0; nn < 4; ++nn)
                acc[mm][nn] = __builtin_amdgcn_mfma_f32_16x16x32_bf16(
                    ah[mm], b1[nn], acc[mm][nn], 0, 0, 0);
    };

    // 2-deep pipeline, x2 unrolled (nk is a multiple of 4)
    load0(0);
    load1(1);
    for (int kc = 0; kc < nk; kc += 2) {
        mfma0();                       // waits only on ar0/b0 (counted vmcnt)
        if (kc + 2 < nk) load0(kc + 2);
        mfma1();
        if (kc + 3 < nk) load1(kc + 3);
    }

    // ---- epilogue: C/D layout col=lane&15, row=(lane>>4)*4+q ----
    #pragma unroll
    for (int mm = 0; mm < 4; ++mm) {
        const int grow = mt * 128 + wr * 64 + mm * 16 + lg * 4;
        #pragma unroll
        for (int nn = 0; nn < 4; ++nn) {
            const int gcol = nb * 128 + wc * 64 + nn * 16 + l15;
            #pragma unroll
            for (int q = 0; q < 4; ++q)
                Y[(size_t)(grow + q) * 1024 + gcol] = acc[mm][nn][q];
        }
    }
}

} // namespace

extern "C" void kernel_launch(void* const* d_in, const int* in_sizes, int n_in,
                              void* d_out, int out_size, void* d_ws, size_t ws_size,
                              hipStream_t stream) {
    const float* x   = (const float*)d_in[0];
    const float* Lre = (const float*)d_in[1];
    const float* Lim = (const float*)d_in[2];
    const float* Bre = (const float*)d_in[3];
    const float* Bim = (const float*)d_in[4];
    const float* Cre = (const float*)d_in[5];
    const float* Cim = (const float*)d_in[6];
    const float* Dm  = (const float*)d_in[7];
    float* y = (float*)d_out;

    const int positions = in_sizes[0] / 1024;          // 32768
    const int mtiles = positions / 128;                // 256

    unsigned short* Wh = (unsigned short*)d_ws;        // 2 MB

    build_w_kernel<<<64 * 64, 256, 0, stream>>>(Lre, Lim, Bre, Bim, Cre, Cim, Dm, Wh);
    gemm_fused_kernel<<<mtiles * 8, 256, 0, stream>>>(x, Wh, y);
}

// Round 11
// 124.399 us; speedup vs baseline: 2.2198x; 2.2198x over previous
//
#include <hip/hip_runtime.h>

// ImageLRU as one GEMM: y[r,:] = W @ x[r,:], W (1024x1024, block-lower-tri)
// built on device. R11 = R9 register-direct GEMM with BN=256 supertiles:
//  - Each block computes 64 rows x 256 cols (4 waves, 1Mx4N, 64x64/wave).
//    A-fragments serve 2x the output columns -> logical A re-reads through
//    L3 halve (the R7-R9 ~121us invariance pointed at L3-BW-bound A traffic).
//  - No LDS, no barriers; 2-deep named-register pipeline (static indexing).
//  - W-fragments direct from tiled Wh (2 MB, L2-resident).
//  - 1-term precision: y = bf16(X) * bf16(W)  (absmax 8192, thr 32768).

namespace {

typedef __attribute__((ext_vector_type(8))) short short8v;
typedef __attribute__((ext_vector_type(4))) float f32x4;

__device__ inline unsigned short f2bf_rne(float f) {
    unsigned u = __builtin_bit_cast(unsigned, f);
    u += 0x7fffu + ((u >> 16) & 1u);
    return (unsigned short)(u >> 16);
}

// Tiled layout for a [128 rows][32 k] bf16 tile: elem (row,k) at
//   tile_base + ((k>>3)<<10) + (row<<3) + (k&7)   (ushort units, 4096/tile)

// ------------- prep: blocks [0,4096) build W; [4096,12288) split X ----------
__global__ __launch_bounds__(256) void prep_kernel(
    const float* __restrict__ X,
    const float* __restrict__ Lre, const float* __restrict__ Lim,
    const float* __restrict__ Bre, const float* __restrict__ Bim,
    const float* __restrict__ Cre, const float* __restrict__ Cim,
    const float* __restrict__ Dm,
    unsigned short* __restrict__ Wh, unsigned short* __restrict__ Xh)
{
    const int t = threadIdx.x;

    if (blockIdx.x < 4096) {
        // ---- build W block (i,j): T = prod of stage factors; W = Re(C*T)+D ----
        const int i = blockIdx.x >> 6, j = blockIdx.x & 63;
        const int k = t >> 4, l = t & 15;

        const int n_g = i * 16 + k;        // W row (n dim)
        const int k_g = j * 16 + l;        // W col (k dim)
        const size_t widx = (((size_t)((n_g >> 7) * 32 + (k_g >> 5))) << 12)
                          + (((k_g >> 3) & 3) << 10) + ((n_g & 127) << 3) + (k_g & 7);

        if (j > i) { Wh[widx] = 0; return; }

        __shared__ float2 Bs[16][16];
        __shared__ float2 M[16][16];
        Bs[k][l] = make_float2(Bre[t], Bim[t]);
        M[k][l]  = make_float2(k == l ? 1.f : 0.f, 0.f);
        const int delta = i - j;
        __syncthreads();

        #pragma unroll
        for (int d = 0; d < 6; ++d) {
            const int s = 1 << d;
            if (delta & s) {
                const float lr = Lre[k], li = Lim[k];
                const float2 m0 = M[k][l];
                M[k][l] = make_float2(lr * m0.x - li * m0.y, lr * m0.y + li * m0.x);
                __syncthreads();
            } else if (j + (delta & (s - 1)) >= s) {
                float2 acc = make_float2(0.f, 0.f);
                #pragma unroll
                for (int m = 0; m < 16; ++m) {
                    const float2 b = Bs[k][m], v = M[m][l];
                    acc.x += b.x * v.x - b.y * v.y;
                    acc.y += b.x * v.y + b.y * v.x;
                }
                __syncthreads();
                M[k][l] = acc;
                __syncthreads();
            }
        }

        float w = 0.f;
        #pragma unroll
        for (int m = 0; m < 16; ++m) {
            const float2 v = M[m][l];
            w += Cre[k * 16 + m] * v.x - Cim[k * 16 + m] * v.y;
        }
        if (i == j) w += Dm[t];
        Wh[widx] = f2bf_rne(w);
    } else {
        // ---- split X tile (mt, kc) -> bf16 tiled layout ----
        const int sid = blockIdx.x - 4096;
        const int mt = sid >> 5;           // 128-row tile (0..255)
        const int kc = sid & 31;           // 32-col chunk
        const size_t tb = ((size_t)(mt * 32 + kc)) << 12;

        #pragma unroll
        for (int p = 0; p < 4; ++p) {
            const int f = p * 256 + t;          // float4 id in [0,1024)
            const int row = f >> 3, c4 = f & 7;
            const float4 v = *reinterpret_cast<const float4*>(
                X + (size_t)(mt * 128 + row) * 1024 + kc * 32 + c4 * 4);
            ushort4 hv;
            hv.x = f2bf_rne(v.x);
            hv.y = f2bf_rne(v.y);
            hv.z = f2bf_rne(v.z);
            hv.w = f2bf_rne(v.w);
            const size_t o = tb + ((size_t)(c4 >> 1) << 10) + (row << 3) + ((c4 & 1) << 2);
            *reinterpret_cast<ushort4*>(Xh + o) = hv;
        }
    }
}

// ------ main GEMM: 64x256 blocks, register pipeline, no LDS, no barriers ----
__global__ __launch_bounds__(256) void gemm_reg_kernel(
    const unsigned short* __restrict__ Xh,
    const unsigned short* __restrict__ Wh,
    float* __restrict__ Y, int m64)
{
    const int bid = blockIdx.x;
    const int sb = 3 - bid / m64;      // 256-col supertile, heavy first (LPT)
    const int mt64 = bid % m64;        // 64-row slab
    const int mt128 = mt64 >> 1;       // 128-row Xh tile index
    const int rbase = (mt64 & 1) * 64; // row base within the Xh tile
    const int t = threadIdx.x;
    const int wcn = t >> 6;            // wave = N-position (4 waves, 1Mx4N)
    const int lane = t & 63;
    const int l15 = lane & 15, lg = lane >> 4;
    const int nb = sb * 2 + (wcn >> 1);        // 128-col W tile
    const int rw = (wcn & 1) * 64;             // row base within W tile
    const int nk = (sb + 1) * 8;       // triangular K-limit (chunks of 32), even

    f32x4 acc[4][4] = {};

    // fragment offsets (ushorts) within a K-chunk tile
    int afo[4], wfo[4];
    #pragma unroll
    for (int mm = 0; mm < 4; ++mm)
        afo[mm] = (lg << 10) + ((rbase + mm * 16 + l15) << 3);
    #pragma unroll
    for (int nn = 0; nn < 4; ++nn)
        wfo[nn] = (lg << 10) + ((rw + nn * 16 + l15) << 3);

    short8v a0[4], b0[4], a1[4], b1[4];

    auto load0 = [&](int kc) {
        const size_t xb = ((size_t)(mt128 * 32 + kc)) << 12;
        const size_t wb = ((size_t)(nb * 32 + kc)) << 12;
        #pragma unroll
        for (int mm = 0; mm < 4; ++mm)
            a0[mm] = *reinterpret_cast<const short8v*>(Xh + xb + afo[mm]);
        #pragma unroll
        for (int nn = 0; nn < 4; ++nn)
            b0[nn] = *reinterpret_cast<const short8v*>(Wh + wb + wfo[nn]);
    };
    auto load1 = [&](int kc) {
        const size_t xb = ((size_t)(mt128 * 32 + kc)) << 12;
        const size_t wb = ((size_t)(nb * 32 + kc)) << 12;
        #pragma unroll
        for (int mm = 0; mm < 4; ++mm)
            a1[mm] = *reinterpret_cast<const short8v*>(Xh + xb + afo[mm]);
        #pragma unroll
        for (int nn = 0; nn < 4; ++nn)
            b1[nn] = *reinterpret_cast<const short8v*>(Wh + wb + wfo[nn]);
    };
    auto mfma0 = [&]() {
        #pragma unroll
        for (int mm = 0; mm < 4; ++mm)
            #pragma unroll
            for (int nn = 0; nn < 4; ++nn)
                acc[mm][nn] = __builtin_amdgcn_mfma_f32_16x16x32_bf16(
                    a0[mm], b0[nn], acc[mm][nn], 0, 0, 0);
    };
    auto mfma1 = [&]() {
        #pragma unroll
        for (int mm = 0; mm < 4; ++mm)
            #pragma unroll
            for (int nn = 0; nn < 4; ++nn)
                acc[mm][nn] = __builtin_amdgcn_mfma_f32_16x16x32_bf16(
                    a1[mm], b1[nn], acc[mm][nn], 0, 0, 0);
    };

    // 2-deep pipeline, x2 unrolled (nk is a multiple of 8)
    load0(0);
    load1(1);
    for (int kc = 0; kc < nk; kc += 2) {
        mfma0();                       // waits only on a0/b0 (counted vmcnt)
        if (kc + 2 < nk) load0(kc + 2);
        mfma1();
        if (kc + 3 < nk) load1(kc + 3);
    }

    // ---- epilogue: C/D layout col=lane&15, row=(lane>>4)*4+q ----
    #pragma unroll
    for (int mm = 0; mm < 4; ++mm) {
        const int grow = mt64 * 64 + mm * 16 + lg * 4;
        #pragma unroll
        for (int nn = 0; nn < 4; ++nn) {
            const int gcol = sb * 256 + wcn * 64 + nn * 16 + l15;
            #pragma unroll
            for (int q = 0; q < 4; ++q)
                Y[(size_t)(grow + q) * 1024 + gcol] = acc[mm][nn][q];
        }
    }
}

} // namespace

extern "C" void kernel_launch(void* const* d_in, const int* in_sizes, int n_in,
                              void* d_out, int out_size, void* d_ws, size_t ws_size,
                              hipStream_t stream) {
    const float* x   = (const float*)d_in[0];
    const float* Lre = (const float*)d_in[1];
    const float* Lim = (const float*)d_in[2];
    const float* Bre = (const float*)d_in[3];
    const float* Bim = (const float*)d_in[4];
    const float* Cre = (const float*)d_in[5];
    const float* Cim = (const float*)d_in[6];
    const float* Dm  = (const float*)d_in[7];
    float* y = (float*)d_out;

    const int positions = in_sizes[0] / 1024;          // 32768
    const int mtiles = positions / 128;                // 256
    const int m64 = positions / 64;                    // 512

    unsigned short* Wh = (unsigned short*)d_ws;        // 2 MB
    unsigned short* Xh = Wh + 1024 * 1024;             // 64 MB

    prep_kernel<<<4096 + mtiles * 32, 256, 0, stream>>>(
        x, Lre, Lim, Bre, Bim, Cre, Cim, Dm, Wh, Xh);
    gemm_reg_kernel<<<m64 * 4, 256, 0, stream>>>(Xh, Wh, y, m64);
}

// Round 12
// 119.811 us; speedup vs baseline: 2.3048x; 1.0383x over previous
//
#include <hip/hip_runtime.h>

// ImageLRU as one GEMM: y[r,:] = W @ x[r,:], W (1024x1024, block-lower-tri)
// built on device. R12: FUSED X->bf16 conversion inside the proven R7 GEMM:
//  - No Xh intermediate (saves 134 MB HBM round-trip + the split_x pass).
//  - A-stage: fp32 global loads issued EARLY (s-linear mapping: row=t&127,
//    g8=t>>7 -> 2-way-free ds_write banks, unlike R5's 4-way), RNE convert,
//    ds_write LATE into the same kg-major LDS image R4/R7 read conflict-free.
//  - W staged via global_load_lds (linear, L2-resident 2 MB), as in R7.
//  - nb-major LPT block order (R4-proven: L3 keeps the X slab resident,
//    FETCH ~84-150 MB, unlike R5/R10's mt-major 300 MB).
//  - 1 barrier per K-chunk, double-buffered; 1-term precision (absmax 8192).

namespace {

typedef __attribute__((ext_vector_type(8))) short short8v;
typedef __attribute__((ext_vector_type(4))) float f32x4;

__device__ inline unsigned short f2bf_rne(float f) {
    unsigned u = __builtin_bit_cast(unsigned, f);
    u += 0x7fffu + ((u >> 16) & 1u);
    return (unsigned short)(u >> 16);
}

__device__ inline void gld_lds16(const unsigned short* g, unsigned short* l) {
    __builtin_amdgcn_global_load_lds(
        (const __attribute__((address_space(1))) unsigned int*)g,
        (__attribute__((address_space(3))) unsigned int*)l, 16, 0, 0);
}

// kg-major tile layout ([128 rows][32 k] bf16, 4096 ushorts): elem (row,k) at
//   base + ((k>>3)<<10) + (row<<3) + (k&7)
// Proven: ds_read_b128 fragments conflict-free (R3/R4 counters = 0).

// ---------------- prep: build Wh (bf16) in tiled layout ----------------
__global__ __launch_bounds__(256) void build_w_kernel(
    const float* __restrict__ Lre, const float* __restrict__ Lim,
    const float* __restrict__ Bre, const float* __restrict__ Bim,
    const float* __restrict__ Cre, const float* __restrict__ Cim,
    const float* __restrict__ Dm,
    unsigned short* __restrict__ Wh)
{
    const int i = blockIdx.x >> 6, j = blockIdx.x & 63;
    const int t = threadIdx.x, k = t >> 4, l = t & 15;

    const int n_g = i * 16 + k;        // W row (n dim)
    const int k_g = j * 16 + l;        // W col (k dim)
    const size_t widx = (((size_t)((n_g >> 7) * 32 + (k_g >> 5))) << 12)
                      + (((k_g >> 3) & 3) << 10) + ((n_g & 127) << 3) + (k_g & 7);

    if (j > i) { Wh[widx] = 0; return; }

    __shared__ float2 Bs[16][16];
    __shared__ float2 M[16][16];
    Bs[k][l] = make_float2(Bre[t], Bim[t]);
    M[k][l]  = make_float2(k == l ? 1.f : 0.f, 0.f);
    const int delta = i - j;
    __syncthreads();

    #pragma unroll
    for (int d = 0; d < 6; ++d) {
        const int s = 1 << d;
        if (delta & s) {
            const float lr = Lre[k], li = Lim[k];
            const float2 m0 = M[k][l];
            M[k][l] = make_float2(lr * m0.x - li * m0.y, lr * m0.y + li * m0.x);
            __syncthreads();
        } else if (j + (delta & (s - 1)) >= s) {
            float2 acc = make_float2(0.f, 0.f);
            #pragma unroll
            for (int m = 0; m < 16; ++m) {
                const float2 b = Bs[k][m], v = M[m][l];
                acc.x += b.x * v.x - b.y * v.y;
                acc.y += b.x * v.y + b.y * v.x;
            }
            __syncthreads();
            M[k][l] = acc;
            __syncthreads();
        }
    }

    float w = 0.f;
    #pragma unroll
    for (int m = 0; m < 16; ++m) {
        const float2 v = M[m][l];
        w += Cre[k * 16 + m] * v.x - Cim[k * 16 + m] * v.y;
    }
    if (i == j) w += Dm[t];
    Wh[widx] = f2bf_rne(w);
}

// ------ main GEMM: fused A-convert (reg-staged), W gld_lds, dbuf LDS --------
__global__ __launch_bounds__(256) void gemm_fused_kernel(
    const float* __restrict__ X,
    const unsigned short* __restrict__ Wh,
    float* __restrict__ Y, int mtiles)
{
    __shared__ alignas(16) unsigned short sA[2][4096];   // A tiles, 16 KB
    __shared__ alignas(16) unsigned short sW[2][4096];   // W tiles, 16 KB

    const int bid = blockIdx.x;
    const int nb = 7 - bid / mtiles;   // heavy N-tiles first (LPT), nb-major
    const int mt = bid % mtiles;
    const int t = threadIdx.x;
    const int wid = t >> 6, lane = t & 63;
    const int wr = wid >> 1, wc = wid & 1;
    const int l15 = lane & 15, lg = lane >> 4;
    const int nk = (nb + 1) * 4;       // triangular K-limit (chunks of 32)

    f32x4 acc[4][4] = {};

    // A staging: thread owns row = t&127 and k-slices {g, g+2}, g = t>>7.
    const int arow = t & 127;
    const int ag0 = t >> 7;            // 0 or 1
    const float* xrow = X + (size_t)(mt * 128 + arow) * 1024;
    const int aoff0 = (ag0 << 10) + (arow << 3);          // ushort offsets
    const int aoff1 = ((ag0 + 2) << 10) + (arow << 3);

    float4 xr[4];                      // 16 floats in flight
    auto x_issue = [&](int kc) {
        const float* s0 = xrow + kc * 32 + ag0 * 8;
        const float* s1 = s0 + 16;     // slice ag0+2
        xr[0] = *reinterpret_cast<const float4*>(s0);
        xr[1] = *reinterpret_cast<const float4*>(s0 + 4);
        xr[2] = *reinterpret_cast<const float4*>(s1);
        xr[3] = *reinterpret_cast<const float4*>(s1 + 4);
    };
    auto cvt8 = [&](const float4& a, const float4& b) -> short8v {
        short8v r;
        r[0] = (short)f2bf_rne(a.x); r[1] = (short)f2bf_rne(a.y);
        r[2] = (short)f2bf_rne(a.z); r[3] = (short)f2bf_rne(a.w);
        r[4] = (short)f2bf_rne(b.x); r[5] = (short)f2bf_rne(b.y);
        r[6] = (short)f2bf_rne(b.z); r[7] = (short)f2bf_rne(b.w);
        return r;
    };
    auto x_write = [&](unsigned short* buf) {
        *reinterpret_cast<short8v*>(buf + aoff0) = cvt8(xr[0], xr[1]);
        *reinterpret_cast<short8v*>(buf + aoff1) = cvt8(xr[2], xr[3]);
    };
    auto w_issue = [&](unsigned short* buf, int kc) {
        const size_t wb = ((size_t)(nb * 32 + kc)) << 12;
        gld_lds16(Wh + wb + t * 8,        buf + t * 8);
        gld_lds16(Wh + wb + 2048 + t * 8, buf + 2048 + t * 8);
    };

    // prologue: fill buf0 for kc=0
    x_issue(0);
    w_issue(sW[0], 0);
    x_write(sA[0]);                    // compiler waits xr loads
    __syncthreads();                   // drains vm+lgkm: buf0 ready

    int cur = 0;
    for (int kc = 0; kc < nk; ++kc) {
        const bool more = (kc + 1 < nk);
        if (more) {
            x_issue(kc + 1);                 // fp32 loads early (latency hidden)
            w_issue(sW[cur ^ 1], kc + 1);    // DMA in flight across MFMA
        }

        short8v ah[4], bh[4];
        #pragma unroll
        for (int mm = 0; mm < 4; ++mm) {
            const int o = (lg << 10) + ((wr * 64 + mm * 16 + l15) << 3);
            ah[mm] = *reinterpret_cast<const short8v*>(sA[cur] + o);
        }
        #pragma unroll
        for (int nn = 0; nn < 4; ++nn) {
            const int o = (lg << 10) + ((wc * 64 + nn * 16 + l15) << 3);
            bh[nn] = *reinterpret_cast<const short8v*>(sW[cur] + o);
        }
        #pragma unroll
        for (int mm = 0; mm < 4; ++mm) {
            #pragma unroll
            for (int nn = 0; nn < 4; ++nn) {
                acc[mm][nn] = __builtin_amdgcn_mfma_f32_16x16x32_bf16(
                    ah[mm], bh[nn], acc[mm][nn], 0, 0, 0);
            }
        }

        if (more) x_write(sA[cur ^ 1]);  // late write into next buf (its last
                                         // readers passed the kc-1 barrier)
        __syncthreads();   // all reads of cur done; next buf fully landed
        cur ^= 1;
    }

    // ---- epilogue: C/D layout col=lane&15, row=(lane>>4)*4+q ----
    #pragma unroll
    for (int mm = 0; mm < 4; ++mm) {
        const int grow = mt * 128 + wr * 64 + mm * 16 + lg * 4;
        #pragma unroll
        for (int nn = 0; nn < 4; ++nn) {
            const int gcol = nb * 128 + wc * 64 + nn * 16 + l15;
            #pragma unroll
            for (int q = 0; q < 4; ++q)
                Y[(size_t)(grow + q) * 1024 + gcol] = acc[mm][nn][q];
        }
    }
}

} // namespace

extern "C" void kernel_launch(void* const* d_in, const int* in_sizes, int n_in,
                              void* d_out, int out_size, void* d_ws, size_t ws_size,
                              hipStream_t stream) {
    const float* x   = (const float*)d_in[0];
    const float* Lre = (const float*)d_in[1];
    const float* Lim = (const float*)d_in[2];
    const float* Bre = (const float*)d_in[3];
    const float* Bim = (const float*)d_in[4];
    const float* Cre = (const float*)d_in[5];
    const float* Cim = (const float*)d_in[6];
    const float* Dm  = (const float*)d_in[7];
    float* y = (float*)d_out;

    const int positions = in_sizes[0] / 1024;          // 32768
    const int mtiles = positions / 128;                // 256

    unsigned short* Wh = (unsigned short*)d_ws;        // 2 MB

    build_w_kernel<<<64 * 64, 256, 0, stream>>>(Lre, Lim, Bre, Bim, Cre, Cim, Dm, Wh);
    gemm_fused_kernel<<<mtiles * 8, 256, 0, stream>>>(x, Wh, y, mtiles);
}